// Round 14
// baseline (2443.189 us; speedup 1.0000x reference)
//
#include <hip/hip_runtime.h>

#define BB 4
#define NN 8192
#define SS 2048
#define KK 16
#define INCH 64
#define HH 64
#define OUTC 128
#define LEAKY_A 0.1f
#define EPSF 1e-5f

__device__ __forceinline__ float sq3(float a, float b, float c) {
    // strict IEEE ((a*a + b*b) + c*c) to match numpy reduction order, no FMA contraction
    return __fadd_rn(__fadd_rn(__fmul_rn(a, a), __fmul_rn(b, b)), __fmul_rn(c, c));
}

__device__ __forceinline__ float leaky_f(float x) { return x >= 0.f ? x : LEAKY_A * x; }

__device__ __forceinline__ int spread3(int v) {
    return (v & 1) | ((v & 2) << 2) | ((v & 4) << 4);
}

__device__ __forceinline__ unsigned long long shfl_xor_u64(unsigned long long v, int off) {
    unsigned lo = (unsigned)v, hi = (unsigned)(v >> 32);
    lo = __shfl_xor(lo, off);
    hi = __shfl_xor(hi, off);
    return ((unsigned long long)hi << 32) | lo;
}

// ---------------- FPS: one block (1024 thr = 16 waves) per batch -------------
// r12/r13 structure (verified ~1755 us) with a cheaper cross-reduce fast path:
// the wave winner is packed into ONE float4 slot {x,y,z, dist-bits}; the
// per-iteration chain is a single b128 LDS read + 4-step DPP max on .w +
// bpermute broadcasts. The b64 skey slot is only read (a) in the rare
// exact-dist-tie fallback (full 64-bit compare, semantics identical) and
// (b) by t==0 to record the winner index (off the serial chain). Bit-exact:
// dist bits roundtrip through __uint_as_float unchanged; skipped updates
// satisfy d > dist under worst-case rounding (margin 1e-5 >> 4 ulp); min()
// over a multiset is order-independent; ties -> max(~idx) as before.
__global__ __launch_bounds__(1024)
void fps_kernel(const float* __restrict__ xyz,   // [B,3,N]
                float* __restrict__ new_xyz,     // [B,S,3]
                float* __restrict__ out0,        // [B,3,S]
                float* __restrict__ out2)        // [B,S] (float indices)
{
    int b = blockIdx.x, t = threadIdx.x;
    int lane = t & 63, wid = t >> 6;
    const float* xb = xyz + (long)b * 3 * NN;

    __shared__ unsigned short perm[NN];          // 16 KB
    __shared__ unsigned int hist[512];           // 2 KB
    __shared__ unsigned int starts[512];         // 2 KB
    __shared__ unsigned int wsum[8];
    __shared__ float wred[16][6];
    __shared__ unsigned long long skey[2][16];   // winner key (tie-fallback / idx)
    __shared__ float4 sval[2][16];               // {x, y, z, dist-bits}
    __shared__ unsigned short pick[SS];          // 4 KB picked indices (LDS only)

    // ---- prologue: load, block bbox, morton codes ----
    float lx[8], ly[8], lz[8];
    float mnx = 3.4e38f, mny = 3.4e38f, mnz = 3.4e38f;
    float mxx = -3.4e38f, mxy = -3.4e38f, mxz = -3.4e38f;
#pragma unroll
    for (int j = 0; j < 8; ++j) {
        int n = t * 8 + j;
        lx[j] = xb[n]; ly[j] = xb[NN + n]; lz[j] = xb[2 * NN + n];
        mnx = fminf(mnx, lx[j]); mxx = fmaxf(mxx, lx[j]);
        mny = fminf(mny, ly[j]); mxy = fmaxf(mxy, ly[j]);
        mnz = fminf(mnz, lz[j]); mxz = fmaxf(mxz, lz[j]);
    }
#pragma unroll
    for (int off = 1; off < 64; off <<= 1) {
        mnx = fminf(mnx, __shfl_xor(mnx, off)); mxx = fmaxf(mxx, __shfl_xor(mxx, off));
        mny = fminf(mny, __shfl_xor(mny, off)); mxy = fmaxf(mxy, __shfl_xor(mxy, off));
        mnz = fminf(mnz, __shfl_xor(mnz, off)); mxz = fmaxf(mxz, __shfl_xor(mxz, off));
    }
    if (lane == 0) {
        wred[wid][0] = mnx; wred[wid][1] = mny; wred[wid][2] = mnz;
        wred[wid][3] = mxx; wred[wid][4] = mxy; wred[wid][5] = mxz;
    }
    if (t < 512) hist[t] = 0;
    __syncthreads();
    mnx = wred[0][0]; mny = wred[0][1]; mnz = wred[0][2];
    mxx = wred[0][3]; mxy = wred[0][4]; mxz = wred[0][5];
#pragma unroll
    for (int w = 1; w < 16; ++w) {
        mnx = fminf(mnx, wred[w][0]); mny = fminf(mny, wred[w][1]); mnz = fminf(mnz, wred[w][2]);
        mxx = fmaxf(mxx, wred[w][3]); mxy = fmaxf(mxy, wred[w][4]); mxz = fmaxf(mxz, wred[w][5]);
    }
    float sclx = 8.0f / fmaxf(mxx - mnx, 1e-9f);
    float scly = 8.0f / fmaxf(mxy - mny, 1e-9f);
    float sclz = 8.0f / fmaxf(mxz - mnz, 1e-9f);
    int mcode[8];
#pragma unroll
    for (int j = 0; j < 8; ++j) {
        int ux = (int)((lx[j] - mnx) * sclx); ux = ux < 0 ? 0 : (ux > 7 ? 7 : ux);
        int uy = (int)((ly[j] - mny) * scly); uy = uy < 0 ? 0 : (uy > 7 ? 7 : uy);
        int uz = (int)((lz[j] - mnz) * sclz); uz = uz < 0 ? 0 : (uz > 7 ? 7 : uz);
        mcode[j] = spread3(ux) | (spread3(uy) << 1) | (spread3(uz) << 2);
        atomicAdd(&hist[mcode[j]], 1u);
    }
    __syncthreads();
    // exclusive scan over 512 bins (waves 0..7)
    unsigned v = 0, incl = 0;
    if (t < 512) {
        v = hist[t];
        incl = v;
#pragma unroll
        for (int d = 1; d < 64; d <<= 1) {
            unsigned u = __shfl_up(incl, d);
            if (lane >= d) incl += u;
        }
        if (lane == 63) wsum[wid] = incl;
    }
    __syncthreads();
    if (t < 512) {
        unsigned off = 0;
        for (int w = 0; w < wid; ++w) off += wsum[w];
        starts[t] = off + incl - v;
    }
    __syncthreads();
#pragma unroll
    for (int j = 0; j < 8; ++j) {
        unsigned pos = atomicAdd(&starts[mcode[j]], 1u);
        perm[pos] = (unsigned short)(t * 8 + j);
    }
    __syncthreads();

    // ---- gather spatially-sorted points, sort each thread's 8 by orig idx ----
    float px[8], py[8], pz[8], dist[8];
    int oi[8];
#pragma unroll
    for (int j = 0; j < 8; ++j) {
        int o = perm[t * 8 + j];
        oi[j] = o;
        px[j] = xb[o]; py[j] = xb[NN + o]; pz[j] = xb[2 * NN + o];
        dist[j] = 1e10f;
    }
#define CSWAP(a, b) { if (oi[a] > oi[b]) { int ti = oi[a]; oi[a] = oi[b]; oi[b] = ti; \
    float tf; tf = px[a]; px[a] = px[b]; px[b] = tf; \
    tf = py[a]; py[a] = py[b]; py[b] = tf; \
    tf = pz[a]; pz[a] = pz[b]; pz[b] = tf; } }
    CSWAP(0,1) CSWAP(2,3) CSWAP(4,5) CSWAP(6,7)
    CSWAP(0,2) CSWAP(1,3) CSWAP(4,6) CSWAP(5,7)
    CSWAP(1,2) CSWAP(5,6)
    CSWAP(0,4) CSWAP(1,5) CSWAP(2,6) CSWAP(3,7)
    CSWAP(2,4) CSWAP(3,5)
    CSWAP(1,2) CSWAP(3,4) CSWAP(5,6)
#undef CSWAP
    // per-thread bbox of its 8 points
    float tbx0 = 3.4e38f, tby0 = 3.4e38f, tbz0 = 3.4e38f;
    float tbx1 = -3.4e38f, tby1 = -3.4e38f, tbz1 = -3.4e38f;
#pragma unroll
    for (int j = 0; j < 8; ++j) {
        tbx0 = fminf(tbx0, px[j]); tbx1 = fmaxf(tbx1, px[j]);
        tby0 = fminf(tby0, py[j]); tby1 = fmaxf(tby1, py[j]);
        tbz0 = fminf(tbz0, pz[j]); tbz1 = fmaxf(tbz1, pz[j]);
    }

    // persistent per-thread state: packed key (kh=dist bits, kl=~idx), coords
    unsigned kh = __float_as_uint(1e10f), kl = 0u;
    float bx = 0.f, by = 0.f, bz = 0.f;
    bool iswin = false;

    if (t == 0) pick[0] = 0;
    float cx = xb[0], cy = xb[NN], cz = xb[2 * NN];   // point 0

// u32 max-reduce step via DPP (bound_ctrl zero-fill: values are dist-bits >=0
// or ~idx >= 0xFFFFE000, so 0 never spuriously wins)
#define DPPMAX(m, CTRL) { \
    unsigned _o = (unsigned)__builtin_amdgcn_update_dpp(0, (int)(m), CTRL, 0xf, 0xf, true); \
    (m) = (_o > (m)) ? _o : (m); \
}

    for (int i = 1; i < SS; ++i) {
        float gx = fmaxf(fmaxf(tbx0 - cx, cx - tbx1), 0.f);
        float gy = fmaxf(fmaxf(tby0 - cy, cy - tby1), 0.f);
        float gz = fmaxf(fmaxf(tbz0 - cz, cz - tbz1), 0.f);
        float lb = gx * gx + gy * gy + gz * gz;
        bool thr_act = lb <= __uint_as_float(kh) * 1.00001f;
        if (__any((int)thr_act)) {
            if (thr_act) {
                float bv = -1.f; int bi = 0; float nbx = 0.f, nby = 0.f, nbz = 0.f;
#pragma unroll
                for (int j = 0; j < 8; ++j) {
                    float dx = __fsub_rn(px[j], cx), dy = __fsub_rn(py[j], cy), dz = __fsub_rn(pz[j], cz);
                    float d = sq3(dx, dy, dz);
                    float nd = fminf(dist[j], d);
                    dist[j] = nd;
                    if (nd > bv) { bv = nd; bi = oi[j]; nbx = px[j]; nby = py[j]; nbz = pz[j]; }
                }
                kh = __float_as_uint(bv); kl = ~(unsigned)bi;
                bx = nbx; by = nby; bz = nbz;
            }
            // intra-wave winner: u32-max on dist bits, exact-tie fallback on kl
            unsigned m = kh;
            DPPMAX(m, 0x111) DPPMAX(m, 0x112) DPPMAX(m, 0x114)
            DPPMAX(m, 0x118) DPPMAX(m, 0x142) DPPMAX(m, 0x143)
            unsigned wmax = (unsigned)__builtin_amdgcn_readlane((int)m, 63);
            unsigned long long mask = __ballot((int)(kh == wmax));
            int wlane;
            if (__popcll(mask) == 1) {
                wlane = (int)__builtin_ctzll(mask);
            } else {
                unsigned t2 = (kh == wmax) ? kl : 0u;
                DPPMAX(t2, 0x111) DPPMAX(t2, 0x112) DPPMAX(t2, 0x114)
                DPPMAX(t2, 0x118) DPPMAX(t2, 0x142) DPPMAX(t2, 0x143)
                unsigned klm = (unsigned)__builtin_amdgcn_readlane((int)t2, 63);
                wlane = (int)__builtin_ctzll(__ballot((int)(kh == wmax && kl == klm)));
            }
            iswin = (lane == wlane);   // keys unique -> exactly one winner lane
        }
        int buf = i & 1;
        if (iswin) {   // persistent winner lane keeps both buffers fresh
            skey[buf][wid] = ((unsigned long long)kh << 32) | kl;
            sval[buf][wid] = make_float4(bx, by, bz, __uint_as_float(kh));
        }
        __syncthreads();   // single barrier
        // fast-path cross-reduce: ONE b128 read; DPP max on dist bits (.w)
        float4 sv = sval[buf][lane & 15];
        unsigned mh = __float_as_uint(sv.w);
        unsigned m2 = mh;
        DPPMAX(m2, 0x111) DPPMAX(m2, 0x112) DPPMAX(m2, 0x114) DPPMAX(m2, 0x118)
        unsigned wh = (unsigned)__builtin_amdgcn_readlane((int)m2, 15);
        unsigned long long mk = __ballot((int)(lane < 16 && mh == wh));
        int widx;
        if (__popcll(mk) == 1) {
            widx = (int)__builtin_ctzll(mk);
        } else {
            // rare exact dist-bit tie across wave winners: full 64-bit compare
            unsigned long long sk = skey[buf][lane & 15];
            unsigned xl = (unsigned)sk;
            unsigned t3 = (lane < 16 && mh == wh) ? xl : 0u;
            DPPMAX(t3, 0x111) DPPMAX(t3, 0x112) DPPMAX(t3, 0x114) DPPMAX(t3, 0x118)
            unsigned wl2 = (unsigned)__builtin_amdgcn_readlane((int)t3, 15);
            widx = (int)__builtin_ctzll(__ballot((int)(lane < 16 && mh == wh && xl == wl2)));
        }
        // all-lane broadcasts (ds_bpermute needs the SOURCE lane active!)
        cx = __shfl(sv.x, widx);
        cy = __shfl(sv.y, widx);
        cz = __shfl(sv.z, widx);
        if (t == 0) {   // off-chain: t0-only LDS read of winner key for the index
            unsigned wl = (unsigned)(skey[buf][widx] & 0xffffffffull);
            pick[i] = (unsigned short)(~wl);
        }
    }
#undef DPPMAX
    __syncthreads();
    for (int i = t; i < SS; i += 1024) {
        int n = pick[i];
        float x = xb[n], y = xb[NN + n], z = xb[2 * NN + n];
        new_xyz[((long)b * SS + i) * 3 + 0] = x;
        new_xyz[((long)b * SS + i) * 3 + 1] = y;
        new_xyz[((long)b * SS + i) * 3 + 2] = z;
        out0[(long)b * 3 * SS + 0 * SS + i] = x;
        out0[(long)b * 3 * SS + 1 * SS + i] = y;
        out0[(long)b * 3 * SS + 2 * SS + i] = z;
        out2[b * SS + i] = (float)n;
    }
}

// ---------------- KNN + BN0/BN1 stats (fused): one wave per center ----------
// r13 fused kernel + (a) XCD-pinned block->batch mapping so each XCD pair
// serves ONE batch (2 MB points resident in its private 4 MB L2 -> gathers
// become L2 hits instead of thrashing across 8 MB), (b) 16-deep gather
// prefetch for the stats phase (all indices broadcast, all gathers issued,
// then compute) instead of 1-in-flight.
__global__ __launch_bounds__(256)
void knn_kernel(const float* __restrict__ xyz,      // [B,3,N]
                const float* __restrict__ new_xyz,  // [B,S,3]
                int* __restrict__ knn_idx,          // [B*S,16]
                const float* __restrict__ points,   // [B,64,N]
                const float* __restrict__ W0, const float* __restrict__ b0,
                const float* __restrict__ W1, const float* __restrict__ b1,
                float* __restrict__ sums)           // [4][64]
{
    int lane = threadIdx.x & 63;
    int wid = threadIdx.x >> 6;
    int xcd = blockIdx.x & 7;
    int b = xcd >> 1;                                   // batch pinned to XCD pair
    int idx_in_b = ((blockIdx.x >> 3) << 1) + (xcd & 1); // 0..511
    int gwave = b * SS + idx_in_b * 4 + wid;            // this wave's center
    const float* xb = xyz + (long)b * 3 * NN;
    float nx = new_xyz[(long)gwave * 3 + 0];
    float ny = new_xyz[(long)gwave * 3 + 1];
    float nz = new_xyz[(long)gwave * 3 + 2];
    float snew = sq3(nx, ny, nz);
    unsigned long long kk[16];
    const unsigned long long KINIT = 0xFF7FFFFF7FFFFFFFull;
#pragma unroll
    for (int j = 0; j < 16; ++j) kk[j] = KINIT;
    unsigned long long wk = KINIT; int ws = 0;
    for (int tix = 0; tix < NN / 64; ++tix) {
        int n = tix * 64 + lane;
        float qx = xb[n], qy = xb[NN + n], qz = xb[2 * NN + n];
        float sx = sq3(qx, qy, qz);
        float dot = __fadd_rn(__fadd_rn(__fmul_rn(nx, qx), __fmul_rn(ny, qy)), __fmul_rn(nz, qz));
        float d = __fsub_rn(__fadd_rn(snew, sx), __fmul_rn(2.0f, dot));
        unsigned ud = __float_as_uint(d);
        ud = ((int)ud < 0) ? ~ud : (ud | 0x80000000u);   // order-monotone map
        unsigned long long key = ((unsigned long long)ud << 32) | (unsigned)n;
        if (key < wk) {
            kk[ws] = key;
            wk = kk[0]; ws = 0;
#pragma unroll
            for (int j = 1; j < 16; ++j) {
                bool g = kk[j] > wk;
                wk = g ? kk[j] : wk; ws = g ? j : ws;
            }
        }
    }
    int myres = 0;
#pragma unroll
    for (int r = 0; r < 16; ++r) {
        unsigned long long mn = kk[0]; int ms = 0;
#pragma unroll
        for (int j = 1; j < 16; ++j) {
            bool l = kk[j] < mn;
            mn = l ? kk[j] : mn; ms = l ? j : ms;
        }
        unsigned long long bm = mn;
#pragma unroll
        for (int off = 1; off < 64; off <<= 1) {
            unsigned long long om = shfl_xor_u64(bm, off);
            if (om < bm) bm = om;
        }
        if (mn == bm) kk[ms] = 0xFFFFFFFFFFFFFFFFull;   // unique key -> one lane marks
        if (lane == r) myres = (int)(unsigned)(bm & 0xffffffffull);
    }
    if (lane < 16) knn_idx[(long)gwave * 16 + lane] = myres;

    // ---- fused BN0/BN1 stats: prefetch all 16 indices + gathers first ----
    const float* pb = points + (long)b * INCH * NN + (long)lane * NN;
    int ns[16];
#pragma unroll
    for (int k = 0; k < 16; ++k) ns[k] = __shfl(myres, k);   // all lanes active
    float gps[16];
#pragma unroll
    for (int k = 0; k < 16; ++k) gps[k] = pb[ns[k]];         // 16 gathers in flight
    float a0 = 0, q0 = 0, a1 = 0, q1 = 0;
#pragma unroll
    for (int k = 0; k < 16; ++k) {
        int n = ns[k];
        float gp = gps[k];
        float x0 = b0[lane];
#pragma unroll
        for (int d = 0; d < 64; ++d)
            x0 = fmaf(__shfl(gp, d), W0[d * 64 + lane], x0);
        float qx = xb[n], qy = xb[NN + n], qz = xb[2 * NN + n];
        float c9[9] = {nx, ny, nz, qx, qy, qz, qx - nx, qy - ny, qz - nz};
        float x1 = b1[lane];
#pragma unroll
        for (int j = 0; j < 9; ++j) x1 = fmaf(c9[j], W1[j * 64 + lane], x1);
        a0 += x0; q0 += x0 * x0; a1 += x1; q1 += x1 * x1;
    }
    __shared__ float red[4][4][64];
    red[0][wid][lane] = a0; red[1][wid][lane] = q0; red[2][wid][lane] = a1; red[3][wid][lane] = q1;
    __syncthreads();
    if (threadIdx.x < 64) {
#pragma unroll
        for (int arr = 0; arr < 4; ++arr) {
            float v = red[arr][0][lane] + red[arr][1][lane] + red[arr][2][lane] + red[arr][3][lane];
            atomicAdd(&sums[arr * 64 + lane], v);
        }
    }
}

// ---------------- per-center fused: bn01 finalize + lse1 -> scores -> softmax ----
__global__ __launch_bounds__(256)
void center_kernel(const float* __restrict__ points, const float* __restrict__ xyz,
                   const float* __restrict__ new_xyz, const int* __restrict__ knn_idx,
                   const float* __restrict__ W0, const float* __restrict__ b0,
                   const float* __restrict__ W1, const float* __restrict__ b1,
                   const float* __restrict__ sums01,
                   const float* __restrict__ g0, const float* __restrict__ be0,
                   const float* __restrict__ g1, const float* __restrict__ be1,
                   const float* __restrict__ Ws,
                   float* __restrict__ features1)   // [B*S,128]
{
    int xcd = blockIdx.x & 7;
    int b = xcd >> 1;
    int s = ((blockIdx.x >> 3) << 1) + (xcd & 1);   // 0..2047
    int bs = (b << 11) + s;
    int wid = threadIdx.x >> 6, lane = threadIdx.x & 63;
    __shared__ float lse[KK][OUTC];
    __shared__ float sraw[KK][OUTC];
    __shared__ float ssl[4][64];
    // folded bn01_finalize (identical arithmetic)
    if (threadIdx.x < 64) {
        int c = threadIdx.x;
        float inv = 1.0f / (float)(BB * SS * KK);
        float m0 = sums01[c] * inv,        v0 = sums01[64 + c] * inv - m0 * m0;
        float m1 = sums01[128 + c] * inv,  v1 = sums01[192 + c] * inv - m1 * m1;
        float s0 = g0[c] / sqrtf(v0 + EPSF);
        float s1 = g1[c] / sqrtf(v1 + EPSF);
        ssl[0][c] = s0; ssl[1][c] = be0[c] - m0 * s0;
        ssl[2][c] = s1; ssl[3][c] = be1[c] - m1 * s1;
    }
    __syncthreads();
    float sc0 = ssl[0][lane], sh0 = ssl[1][lane], sc1 = ssl[2][lane], sh1 = ssl[3][lane];
    float nx = new_xyz[(long)bs * 3], ny = new_xyz[(long)bs * 3 + 1], nz = new_xyz[(long)bs * 3 + 2];
    const float* xb = xyz + (long)b * 3 * NN;
    const float* pb = points + (long)b * INCH * NN + (long)lane * NN;
    int n4[4]; float gp4[4];
#pragma unroll
    for (int kk = 0; kk < 4; ++kk) n4[kk] = knn_idx[(long)bs * 16 + wid * 4 + kk];
#pragma unroll
    for (int kk = 0; kk < 4; ++kk) gp4[kk] = pb[n4[kk]];   // 4 gathers in flight
#pragma unroll
    for (int kk = 0; kk < 4; ++kk) {
        int k = wid * 4 + kk;
        int n = n4[kk];
        float gp = gp4[kk];
        float x0 = b0[lane];
#pragma unroll
        for (int d = 0; d < 64; ++d)
            x0 = fmaf(__shfl(gp, d), W0[d * 64 + lane], x0);
        float qx = xb[n], qy = xb[NN + n], qz = xb[2 * NN + n];
        float c9[9] = {nx, ny, nz, qx, qy, qz, qx - nx, qy - ny, qz - nz};
        float x1 = b1[lane];
#pragma unroll
        for (int j = 0; j < 9; ++j) x1 = fmaf(c9[j], W1[j * 64 + lane], x1);
        x0 = leaky_f(x0 * sc0 + sh0);
        x1 = leaky_f(x1 * sc1 + sh1);
        lse[k][lane] = x1;        // channels 0..63 : lse_part (W1 path)
        lse[k][64 + lane] = x0;   // channels 64..127 : new_points (W0 path)
    }
    __syncthreads();
    // scores raw: sraw[k][d] = sum_c lse[k][c]*Ws[c][d]
    int d = threadIdx.x & 127;
    int kg = threadIdx.x >> 7;   // 0..1 -> 8 k's each
    float acc[8];
#pragma unroll
    for (int i = 0; i < 8; ++i) acc[i] = 0.f;
    for (int c = 0; c < OUTC; ++c) {
        float w = Ws[c * OUTC + d];
#pragma unroll
        for (int i = 0; i < 8; ++i) acc[i] = fmaf(lse[kg * 8 + i][c], w, acc[i]);
    }
#pragma unroll
    for (int i = 0; i < 8; ++i) sraw[kg * 8 + i][d] = leaky_f(acc[i]);
    __syncthreads();
    if (threadIdx.x < OUTC) {
        int dd = threadIdx.x;
        float vals[KK];
        float mx = -3.4e38f;
#pragma unroll
        for (int k = 0; k < KK; ++k) { vals[k] = sraw[k][dd]; mx = fmaxf(mx, vals[k]); }
        float sum = 0.f;
#pragma unroll
        for (int k = 0; k < KK; ++k) { vals[k] = __expf(vals[k] - mx); sum += vals[k]; }
        float invs = 1.0f / sum;
        float feat = 0.f;
#pragma unroll
        for (int k = 0; k < KK; ++k) feat = fmaf(vals[k] * invs, lse[k][dd], feat);
        features1[(long)bs * OUTC + dd] = feat;
    }
}

// ---------------- mlp2 GEMM + stats -------------------
__global__ __launch_bounds__(256)
void mlp2_kernel(const float* __restrict__ features1,  // [B*S,128]
                 const float* __restrict__ W2, const float* __restrict__ b2,
                 float* __restrict__ x2,               // [B*S,128]
                 float* __restrict__ sums2)            // [2][128]
{
    int p0 = blockIdx.x * 16;
    __shared__ float f[16][OUTC];
    for (int i = threadIdx.x; i < 16 * OUTC; i += 256)
        f[i >> 7][i & 127] = features1[(long)p0 * OUTC + i];
    __syncthreads();
    int d = threadIdx.x & 127;
    int g = threadIdx.x >> 7;
    float acc[8];
#pragma unroll
    for (int i = 0; i < 8; ++i) acc[i] = b2[d];
    for (int c = 0; c < OUTC; ++c) {
        float w = W2[c * OUTC + d];
#pragma unroll
        for (int i = 0; i < 8; ++i) acc[i] = fmaf(f[g * 8 + i][c], w, acc[i]);
    }
    float s = 0.f, q = 0.f;
#pragma unroll
    for (int i = 0; i < 8; ++i) {
        x2[(long)(p0 + g * 8 + i) * OUTC + d] = acc[i];
        s += acc[i]; q += acc[i] * acc[i];
    }
    __shared__ float rs[2][2][OUTC];
    rs[0][g][d] = s; rs[1][g][d] = q;
    __syncthreads();
    if (threadIdx.x < OUTC) {
        atomicAdd(&sums2[d],        rs[0][0][d] + rs[0][1][d]);
        atomicAdd(&sums2[OUTC + d], rs[1][0][d] + rs[1][1][d]);
    }
}

// ---------------- out1 (+ folded bn2 finalize) -------------------
__global__ __launch_bounds__(256)
void out1_kernel(const float* __restrict__ x2, const float* __restrict__ sums2,
                 const float* __restrict__ g2, const float* __restrict__ be2,
                 float* __restrict__ out1)   // [B,128,S]
{
    int bc = blockIdx.x;
    int b = bc >> 7, c = bc & 127;
    float inv = 1.0f / (float)(BB * SS);
    float m = sums2[c] * inv, v = sums2[OUTC + c] * inv - m * m;
    float sc = g2[c] / sqrtf(v + EPSF);
    float sh = be2[c] - m * sc;
    for (int s = threadIdx.x; s < SS; s += 256) {
        float val = x2[((long)(b * SS + s)) * OUTC + c] * sc + sh;
        out1[(long)b * OUTC * SS + (long)c * SS + s] = leaky_f(val);
    }
}

extern "C" void kernel_launch(void* const* d_in, const int* in_sizes, int n_in,
                              void* d_out, int out_size, void* d_ws, size_t ws_size,
                              hipStream_t stream)
{
    const float* xyz    = (const float*)d_in[0];
    const float* points = (const float*)d_in[1];
    const float* W0  = (const float*)d_in[2];
    const float* b0  = (const float*)d_in[3];
    const float* g0  = (const float*)d_in[4];
    const float* be0 = (const float*)d_in[5];
    const float* W1  = (const float*)d_in[6];
    const float* b1  = (const float*)d_in[7];
    const float* g1  = (const float*)d_in[8];
    const float* be1 = (const float*)d_in[9];
    const float* Ws  = (const float*)d_in[10];
    const float* W2  = (const float*)d_in[11];
    const float* b2  = (const float*)d_in[12];
    const float* g2  = (const float*)d_in[13];
    const float* be2 = (const float*)d_in[14];

    char* ws = (char*)d_ws;
    float* nxyz   = (float*)(ws + 32768);        // 98304 B
    int*   knn_i  = (int*)(ws + 131072);         // 524288 B
    float* sums01 = (float*)(ws + 655360);       // 1024 B
    float* sums2  = (float*)(ws + 656384);       // 1024 B
    float* feat1  = (float*)(ws + 659456);       // 4 MB
    float* x2     = (float*)(ws + 659456 + 4194304); // 4 MB

    float* out0 = (float*)d_out;                       // [B,3,S]
    float* out1 = out0 + (long)BB * 3 * SS;            // [B,128,S]
    float* out2 = out1 + (long)BB * OUTC * SS;         // [B,S] float idx

    hipMemsetAsync(sums01, 0, 2048, stream);  // zero sums01 + sums2 (contiguous)

    fps_kernel<<<BB, 1024, 0, stream>>>(xyz, nxyz, out0, out2);
    knn_kernel<<<(BB * SS) / 4, 256, 0, stream>>>(xyz, nxyz, knn_i, points, W0, b0, W1, b1, sums01);
    center_kernel<<<BB * SS, 256, 0, stream>>>(points, xyz, nxyz, knn_i, W0, b0, W1, b1,
                                               sums01, g0, be0, g1, be1, Ws, feat1);
    mlp2_kernel<<<(BB * SS) / 16, 256, 0, stream>>>(feat1, W2, b2, x2, sums2);
    out1_kernel<<<BB * OUTC, 256, 0, stream>>>(x2, sums2, g2, be2, out1);
}

// Round 15
// 2373.328 us; speedup vs baseline: 1.0294x; 1.0294x over previous
//
#include <hip/hip_runtime.h>

#define BB 4
#define NN 8192
#define SS 2048
#define KK 16
#define INCH 64
#define HH 64
#define OUTC 128
#define LEAKY_A 0.1f
#define EPSF 1e-5f

__device__ __forceinline__ float sq3(float a, float b, float c) {
    // strict IEEE ((a*a + b*b) + c*c) to match numpy reduction order, no FMA contraction
    return __fadd_rn(__fadd_rn(__fmul_rn(a, a), __fmul_rn(b, b)), __fmul_rn(c, c));
}

__device__ __forceinline__ float leaky_f(float x) { return x >= 0.f ? x : LEAKY_A * x; }

__device__ __forceinline__ int spread3(int v) {
    return (v & 1) | ((v & 2) << 2) | ((v & 4) << 4);
}

__device__ __forceinline__ unsigned long long shfl_xor_u64(unsigned long long v, int off) {
    unsigned lo = (unsigned)v, hi = (unsigned)(v >> 32);
    lo = __shfl_xor(lo, off);
    hi = __shfl_xor(hi, off);
    return ((unsigned long long)hi << 32) | lo;
}

// ---------------- FPS: one block (1024 thr = 16 waves) per batch -------------
// Best-verified configuration (round 10, 2384.6 us total): Morton sort, 8
// pts/thread in regs, per-thread bbox skip, packed-key argmax key=(dist bits
// <<32)|~idx (tie -> lowest orig index); single barrier per iteration;
// double-buffered slots + persistent winner lane; all waves redundantly
// cross-reduce the 16 slots via u32 DPP fastpath with exact-tie fallback;
// winner index read via readlane (exec-independent). Bit-exact vs reference:
// skipped updates satisfy d > dist under worst-case rounding (margin 1e-5 >>
// 4 ulp); min() over a multiset is order-independent; dist>=0 so u32 bit
// order = float order.
__global__ __launch_bounds__(1024)
void fps_kernel(const float* __restrict__ xyz,   // [B,3,N]
                int* __restrict__ fps_idx,       // [B,S]
                float* __restrict__ new_xyz,     // [B,S,3]
                float* __restrict__ out0,        // [B,3,S]
                float* __restrict__ out2)        // [B,S] (float indices)
{
    int b = blockIdx.x, t = threadIdx.x;
    int lane = t & 63, wid = t >> 6;
    const float* xb = xyz + (long)b * 3 * NN;

    __shared__ unsigned short perm[NN];          // 16 KB
    __shared__ unsigned int hist[512];           // 2 KB
    __shared__ unsigned int starts[512];         // 2 KB
    __shared__ unsigned int wsum[8];
    __shared__ float wred[16][6];
    __shared__ unsigned long long skey[2][16];   // per-wave winner key (dbuf)
    __shared__ float4 sval[2][16];               // per-wave winner coords

    // ---- prologue: load, block bbox, morton codes ----
    float lx[8], ly[8], lz[8];
    float mnx = 3.4e38f, mny = 3.4e38f, mnz = 3.4e38f;
    float mxx = -3.4e38f, mxy = -3.4e38f, mxz = -3.4e38f;
#pragma unroll
    for (int j = 0; j < 8; ++j) {
        int n = t * 8 + j;
        lx[j] = xb[n]; ly[j] = xb[NN + n]; lz[j] = xb[2 * NN + n];
        mnx = fminf(mnx, lx[j]); mxx = fmaxf(mxx, lx[j]);
        mny = fminf(mny, ly[j]); mxy = fmaxf(mxy, ly[j]);
        mnz = fminf(mnz, lz[j]); mxz = fmaxf(mxz, lz[j]);
    }
#pragma unroll
    for (int off = 1; off < 64; off <<= 1) {
        mnx = fminf(mnx, __shfl_xor(mnx, off)); mxx = fmaxf(mxx, __shfl_xor(mxx, off));
        mny = fminf(mny, __shfl_xor(mny, off)); mxy = fmaxf(mxy, __shfl_xor(mxy, off));
        mnz = fminf(mnz, __shfl_xor(mnz, off)); mxz = fmaxf(mxz, __shfl_xor(mxz, off));
    }
    if (lane == 0) {
        wred[wid][0] = mnx; wred[wid][1] = mny; wred[wid][2] = mnz;
        wred[wid][3] = mxx; wred[wid][4] = mxy; wred[wid][5] = mxz;
    }
    if (t < 512) hist[t] = 0;
    __syncthreads();
    mnx = wred[0][0]; mny = wred[0][1]; mnz = wred[0][2];
    mxx = wred[0][3]; mxy = wred[0][4]; mxz = wred[0][5];
#pragma unroll
    for (int w = 1; w < 16; ++w) {
        mnx = fminf(mnx, wred[w][0]); mny = fminf(mny, wred[w][1]); mnz = fminf(mnz, wred[w][2]);
        mxx = fmaxf(mxx, wred[w][3]); mxy = fmaxf(mxy, wred[w][4]); mxz = fmaxf(mxz, wred[w][5]);
    }
    float sclx = 8.0f / fmaxf(mxx - mnx, 1e-9f);
    float scly = 8.0f / fmaxf(mxy - mny, 1e-9f);
    float sclz = 8.0f / fmaxf(mxz - mnz, 1e-9f);
    int mcode[8];
#pragma unroll
    for (int j = 0; j < 8; ++j) {
        int ux = (int)((lx[j] - mnx) * sclx); ux = ux < 0 ? 0 : (ux > 7 ? 7 : ux);
        int uy = (int)((ly[j] - mny) * scly); uy = uy < 0 ? 0 : (uy > 7 ? 7 : uy);
        int uz = (int)((lz[j] - mnz) * sclz); uz = uz < 0 ? 0 : (uz > 7 ? 7 : uz);
        mcode[j] = spread3(ux) | (spread3(uy) << 1) | (spread3(uz) << 2);
        atomicAdd(&hist[mcode[j]], 1u);
    }
    __syncthreads();
    // exclusive scan over 512 bins (waves 0..7)
    unsigned v = 0, incl = 0;
    if (t < 512) {
        v = hist[t];
        incl = v;
#pragma unroll
        for (int d = 1; d < 64; d <<= 1) {
            unsigned u = __shfl_up(incl, d);
            if (lane >= d) incl += u;
        }
        if (lane == 63) wsum[wid] = incl;
    }
    __syncthreads();
    if (t < 512) {
        unsigned off = 0;
        for (int w = 0; w < wid; ++w) off += wsum[w];
        starts[t] = off + incl - v;
    }
    __syncthreads();
#pragma unroll
    for (int j = 0; j < 8; ++j) {
        unsigned pos = atomicAdd(&starts[mcode[j]], 1u);
        perm[pos] = (unsigned short)(t * 8 + j);
    }
    __syncthreads();

    // ---- gather spatially-sorted points, sort each thread's 8 by orig idx ----
    float px[8], py[8], pz[8], dist[8];
    int oi[8];
#pragma unroll
    for (int j = 0; j < 8; ++j) {
        int o = perm[t * 8 + j];
        oi[j] = o;
        px[j] = xb[o]; py[j] = xb[NN + o]; pz[j] = xb[2 * NN + o];
        dist[j] = 1e10f;
    }
#define CSWAP(a, b) { if (oi[a] > oi[b]) { int ti = oi[a]; oi[a] = oi[b]; oi[b] = ti; \
    float tf; tf = px[a]; px[a] = px[b]; px[b] = tf; \
    tf = py[a]; py[a] = py[b]; py[b] = tf; \
    tf = pz[a]; pz[a] = pz[b]; pz[b] = tf; } }
    CSWAP(0,1) CSWAP(2,3) CSWAP(4,5) CSWAP(6,7)
    CSWAP(0,2) CSWAP(1,3) CSWAP(4,6) CSWAP(5,7)
    CSWAP(1,2) CSWAP(5,6)
    CSWAP(0,4) CSWAP(1,5) CSWAP(2,6) CSWAP(3,7)
    CSWAP(2,4) CSWAP(3,5)
    CSWAP(1,2) CSWAP(3,4) CSWAP(5,6)
#undef CSWAP
    // per-thread bbox of its 8 points
    float tbx0 = 3.4e38f, tby0 = 3.4e38f, tbz0 = 3.4e38f;
    float tbx1 = -3.4e38f, tby1 = -3.4e38f, tbz1 = -3.4e38f;
#pragma unroll
    for (int j = 0; j < 8; ++j) {
        tbx0 = fminf(tbx0, px[j]); tbx1 = fmaxf(tbx1, px[j]);
        tby0 = fminf(tby0, py[j]); tby1 = fmaxf(tby1, py[j]);
        tbz0 = fminf(tbz0, pz[j]); tbz1 = fmaxf(tbz1, pz[j]);
    }

    // persistent per-thread state: packed key (kh=dist bits, kl=~idx), coords
    unsigned kh = __float_as_uint(1e10f), kl = 0u;
    float bx = 0.f, by = 0.f, bz = 0.f;
    bool iswin = false;

    if (t == 0) fps_idx[b * SS] = 0;
    float cx = xb[0], cy = xb[NN], cz = xb[2 * NN];   // point 0

// u32 max-reduce step via DPP (bound_ctrl zero-fill: values are dist-bits >=0
// or ~idx >= 0xFFFFE000, so 0 never spuriously wins)
#define DPPMAX(m, CTRL) { \
    unsigned _o = (unsigned)__builtin_amdgcn_update_dpp(0, (int)(m), CTRL, 0xf, 0xf, true); \
    (m) = (_o > (m)) ? _o : (m); \
}

    for (int i = 1; i < SS; ++i) {
        // conservative lower bound of squared distance from c to this thread's bbox
        float gx = fmaxf(fmaxf(tbx0 - cx, cx - tbx1), 0.f);
        float gy = fmaxf(fmaxf(tby0 - cy, cy - tby1), 0.f);
        float gz = fmaxf(fmaxf(tbz0 - cz, cz - tbz1), 0.f);
        float lb = gx * gx + gy * gy + gz * gz;
        bool thr_act = lb <= __uint_as_float(kh) * 1.00001f;
        if (__any((int)thr_act)) {
            if (thr_act) {
                float bv = -1.f; int bi = 0; float nbx = 0.f, nby = 0.f, nbz = 0.f;
#pragma unroll
                for (int j = 0; j < 8; ++j) {
                    float dx = __fsub_rn(px[j], cx), dy = __fsub_rn(py[j], cy), dz = __fsub_rn(pz[j], cz);
                    float d = sq3(dx, dy, dz);
                    float nd = fminf(dist[j], d);
                    dist[j] = nd;
                    if (nd > bv) { bv = nd; bi = oi[j]; nbx = px[j]; nby = py[j]; nbz = pz[j]; }
                }
                kh = __float_as_uint(bv); kl = ~(unsigned)bi;
                bx = nbx; by = nby; bz = nbz;
            }
            // intra-wave winner: u32-max on dist bits, exact-tie fallback on kl
            unsigned m = kh;
            DPPMAX(m, 0x111) DPPMAX(m, 0x112) DPPMAX(m, 0x114)
            DPPMAX(m, 0x118) DPPMAX(m, 0x142) DPPMAX(m, 0x143)
            unsigned wmax = (unsigned)__builtin_amdgcn_readlane((int)m, 63);
            unsigned long long mask = __ballot((int)(kh == wmax));
            int wlane;
            if (__popcll(mask) == 1) {
                wlane = (int)__builtin_ctzll(mask);
            } else {
                unsigned t2 = (kh == wmax) ? kl : 0u;
                DPPMAX(t2, 0x111) DPPMAX(t2, 0x112) DPPMAX(t2, 0x114)
                DPPMAX(t2, 0x118) DPPMAX(t2, 0x142) DPPMAX(t2, 0x143)
                unsigned klm = (unsigned)__builtin_amdgcn_readlane((int)t2, 63);
                wlane = (int)__builtin_ctzll(__ballot((int)(kh == wmax && kl == klm)));
            }
            iswin = (lane == wlane);   // keys unique -> exactly one winner lane
        }
        int buf = i & 1;
        if (iswin) {   // persistent winner lane keeps both buffers fresh
            skey[buf][wid] = ((unsigned long long)kh << 32) | kl;
            sval[buf][wid] = make_float4(bx, by, bz, 0.f);
        }
        __syncthreads();   // single barrier: all slots for this iteration current
        // all waves redundantly cross-reduce the 16 slots (light u32 path)
        unsigned long long sk = skey[buf][lane & 15];
        unsigned xh = (unsigned)(sk >> 32), xl = (unsigned)sk;
        unsigned m2 = xh;
        DPPMAX(m2, 0x111) DPPMAX(m2, 0x112) DPPMAX(m2, 0x114) DPPMAX(m2, 0x118)
        unsigned wh = (unsigned)__builtin_amdgcn_readlane((int)m2, 15);
        unsigned long long mk = __ballot((int)(lane < 16 && xh == wh));
        int widx;
        if (__popcll(mk) == 1) {
            widx = (int)__builtin_ctzll(mk);
        } else {
            unsigned t3 = (lane < 16 && xh == wh) ? xl : 0u;
            DPPMAX(t3, 0x111) DPPMAX(t3, 0x112) DPPMAX(t3, 0x114) DPPMAX(t3, 0x118)
            unsigned wl2 = (unsigned)__builtin_amdgcn_readlane((int)t3, 15);
            widx = (int)__builtin_ctzll(__ballot((int)(lane < 16 && xh == wh && xl == wl2)));
        }
        float4 wv = sval[buf][widx];   // broadcast LDS read
        cx = wv.x; cy = wv.y; cz = wv.z;
        if (t == 0) {
            unsigned wl = (unsigned)__builtin_amdgcn_readlane((int)xl, widx);
            fps_idx[b * SS + i] = (int)(~wl);
        }
    }
#undef DPPMAX
    __syncthreads();
    for (int i = t; i < SS; i += 1024) {
        int n = fps_idx[b * SS + i];
        float x = xb[n], y = xb[NN + n], z = xb[2 * NN + n];
        new_xyz[((long)b * SS + i) * 3 + 0] = x;
        new_xyz[((long)b * SS + i) * 3 + 1] = y;
        new_xyz[((long)b * SS + i) * 3 + 2] = z;
        out0[(long)b * 3 * SS + 0 * SS + i] = x;
        out0[(long)b * 3 * SS + 1 * SS + i] = y;
        out0[(long)b * 3 * SS + 2 * SS + i] = z;
        out2[b * SS + i] = (float)n;
    }
}

// ---------------- KNN: one wave per center -------------------
// Unsorted replace-the-max top-16: per lane, 16 u64 keys = (ordered-dist-bits
// <<32)|idx. Monotone float->uint map preserves float order (d is never -0:
// IEEE RN gives x-x=+0), so key order = (d asc, idx asc) — identical to the
// reference top_k tie semantics. Extraction: 16 rounds of per-lane min +
// wave-min shuffle reduce; no LDS at all.
__global__ __launch_bounds__(256)
void knn_kernel(const float* __restrict__ xyz,      // [B,3,N]
                const float* __restrict__ new_xyz,  // [B,S,3]
                int* __restrict__ knn_idx)          // [B*S,16]
{
    int gwave = (blockIdx.x * 256 + threadIdx.x) >> 6;
    int lane = threadIdx.x & 63;
    if (gwave >= BB * SS) return;
    int b = gwave / SS;
    const float* xb = xyz + (long)b * 3 * NN;
    float nx = new_xyz[(long)gwave * 3 + 0];
    float ny = new_xyz[(long)gwave * 3 + 1];
    float nz = new_xyz[(long)gwave * 3 + 2];
    float snew = sq3(nx, ny, nz);
    unsigned long long kk[16];
    const unsigned long long KINIT = 0xFF7FFFFF7FFFFFFFull;
#pragma unroll
    for (int j = 0; j < 16; ++j) kk[j] = KINIT;
    unsigned long long wk = KINIT; int ws = 0;
    for (int tix = 0; tix < NN / 64; ++tix) {
        int n = tix * 64 + lane;
        float qx = xb[n], qy = xb[NN + n], qz = xb[2 * NN + n];
        float sx = sq3(qx, qy, qz);
        float dot = __fadd_rn(__fadd_rn(__fmul_rn(nx, qx), __fmul_rn(ny, qy)), __fmul_rn(nz, qz));
        float d = __fsub_rn(__fadd_rn(snew, sx), __fmul_rn(2.0f, dot));
        unsigned ud = __float_as_uint(d);
        ud = ((int)ud < 0) ? ~ud : (ud | 0x80000000u);   // order-monotone map
        unsigned long long key = ((unsigned long long)ud << 32) | (unsigned)n;
        if (key < wk) {
            kk[ws] = key;
            wk = kk[0]; ws = 0;
#pragma unroll
            for (int j = 1; j < 16; ++j) {
                bool g = kk[j] > wk;
                wk = g ? kk[j] : wk; ws = g ? j : ws;
            }
        }
    }
    int myres = 0;
#pragma unroll
    for (int r = 0; r < 16; ++r) {
        unsigned long long mn = kk[0]; int ms = 0;
#pragma unroll
        for (int j = 1; j < 16; ++j) {
            bool l = kk[j] < mn;
            mn = l ? kk[j] : mn; ms = l ? j : ms;
        }
        unsigned long long bm = mn;
#pragma unroll
        for (int off = 1; off < 64; off <<= 1) {
            unsigned long long om = shfl_xor_u64(bm, off);
            if (om < bm) bm = om;
        }
        if (mn == bm) kk[ms] = 0xFFFFFFFFFFFFFFFFull;   // unique key -> one lane marks
        if (lane == r) myres = (int)(unsigned)(bm & 0xffffffffull);
    }
    if (lane < 16) knn_idx[(long)gwave * 16 + lane] = myres;
}

// ---------------- BN0/BN1 stats pass -------------------
__global__ __launch_bounds__(256)
void mlp01_stats_kernel(const float* __restrict__ points,   // [B,64,N]
                        const float* __restrict__ xyz,      // [B,3,N]
                        const float* __restrict__ new_xyz,  // [B,S,3]
                        const int* __restrict__ knn_idx,    // [B*S,16]
                        const float* __restrict__ W0, const float* __restrict__ b0,
                        const float* __restrict__ W1, const float* __restrict__ b1,
                        float* __restrict__ sums)           // [4][64]
{
    int wid = threadIdx.x >> 6, lane = threadIdx.x & 63;
    int xcd = blockIdx.x & 7;
    int b = xcd >> 1;                                  // batch pinned to XCD pair
    int idx_in_b = ((blockIdx.x >> 3) << 1) + (xcd & 1);  // 0..511
    long base = ((long)b * 512 + idx_in_b) * 64 + wid * 16;
    const float* pb = points + (long)b * INCH * NN + (long)lane * NN;
    const float* xb = xyz + (long)b * 3 * NN;
    float a0 = 0, q0 = 0, a1 = 0, q1 = 0;
#pragma unroll
    for (int half = 0; half < 2; ++half) {
        int ns[8]; float gps[8];
#pragma unroll
        for (int j = 0; j < 8; ++j) ns[j] = knn_idx[base + half * 8 + j];
#pragma unroll
        for (int j = 0; j < 8; ++j) gps[j] = pb[ns[j]];   // 8 gathers in flight
#pragma unroll
        for (int j = 0; j < 8; ++j) {
            long pos = base + half * 8 + j;
            int bs = (int)(pos >> 4);
            int n = ns[j];
            float gp = gps[j];
            float x0 = b0[lane];
#pragma unroll
            for (int d = 0; d < 64; ++d)
                x0 = fmaf(__shfl(gp, d), W0[d * 64 + lane], x0);
            float nx = new_xyz[(long)bs * 3], ny = new_xyz[(long)bs * 3 + 1], nz = new_xyz[(long)bs * 3 + 2];
            float qx = xb[n], qy = xb[NN + n], qz = xb[2 * NN + n];
            float c9[9] = {nx, ny, nz, qx, qy, qz, qx - nx, qy - ny, qz - nz};
            float x1 = b1[lane];
#pragma unroll
            for (int jj = 0; jj < 9; ++jj) x1 = fmaf(c9[jj], W1[jj * 64 + lane], x1);
            a0 += x0; q0 += x0 * x0; a1 += x1; q1 += x1 * x1;
        }
    }
    __shared__ float red[4][4][64];
    red[0][wid][lane] = a0; red[1][wid][lane] = q0; red[2][wid][lane] = a1; red[3][wid][lane] = q1;
    __syncthreads();
    if (threadIdx.x < 64) {
#pragma unroll
        for (int arr = 0; arr < 4; ++arr) {
            float v = red[arr][0][lane] + red[arr][1][lane] + red[arr][2][lane] + red[arr][3][lane];
            atomicAdd(&sums[arr * 64 + lane], v);
        }
    }
}

__global__ void bn01_finalize(const float* __restrict__ sums,
                              const float* __restrict__ g0, const float* __restrict__ be0,
                              const float* __restrict__ g1, const float* __restrict__ be1,
                              float* __restrict__ ss01)
{
    int c = threadIdx.x;  // 64
    float inv = 1.0f / (float)(BB * SS * KK);
    float m0 = sums[c] * inv,        v0 = sums[64 + c] * inv - m0 * m0;
    float m1 = sums[128 + c] * inv,  v1 = sums[192 + c] * inv - m1 * m1;
    float sc0 = g0[c] / sqrtf(v0 + EPSF);
    float sc1 = g1[c] / sqrtf(v1 + EPSF);
    ss01[c] = sc0;        ss01[64 + c] = be0[c] - m0 * sc0;
    ss01[128 + c] = sc1;  ss01[192 + c] = be1[c] - m1 * sc1;
}

// ---------------- per-center fused: lse1 -> scores -> softmax -> features1 ----------
__global__ __launch_bounds__(256)
void center_kernel(const float* __restrict__ points, const float* __restrict__ xyz,
                   const float* __restrict__ new_xyz, const int* __restrict__ knn_idx,
                   const float* __restrict__ W0, const float* __restrict__ b0,
                   const float* __restrict__ W1, const float* __restrict__ b1,
                   const float* __restrict__ ss01, const float* __restrict__ Ws,
                   float* __restrict__ features1)   // [B*S,128]
{
    int xcd = blockIdx.x & 7;
    int b = xcd >> 1;
    int s = ((blockIdx.x >> 3) << 1) + (xcd & 1);   // 0..2047
    int bs = (b << 11) + s;
    int wid = threadIdx.x >> 6, lane = threadIdx.x & 63;
    __shared__ float lse[KK][OUTC];
    __shared__ float sraw[KK][OUTC];
    float sc0 = ss01[lane], sh0 = ss01[64 + lane], sc1 = ss01[128 + lane], sh1 = ss01[192 + lane];
    float nx = new_xyz[(long)bs * 3], ny = new_xyz[(long)bs * 3 + 1], nz = new_xyz[(long)bs * 3 + 2];
    const float* xb = xyz + (long)b * 3 * NN;
    const float* pb = points + (long)b * INCH * NN + (long)lane * NN;
    int n4[4]; float gp4[4];
#pragma unroll
    for (int kk = 0; kk < 4; ++kk) n4[kk] = knn_idx[(long)bs * 16 + wid * 4 + kk];
#pragma unroll
    for (int kk = 0; kk < 4; ++kk) gp4[kk] = pb[n4[kk]];   // 4 gathers in flight
#pragma unroll
    for (int kk = 0; kk < 4; ++kk) {
        int k = wid * 4 + kk;
        int n = n4[kk];
        float gp = gp4[kk];
        float x0 = b0[lane];
#pragma unroll
        for (int d = 0; d < 64; ++d)
            x0 = fmaf(__shfl(gp, d), W0[d * 64 + lane], x0);
        float qx = xb[n], qy = xb[NN + n], qz = xb[2 * NN + n];
        float c9[9] = {nx, ny, nz, qx, qy, qz, qx - nx, qy - ny, qz - nz};
        float x1 = b1[lane];
#pragma unroll
        for (int j = 0; j < 9; ++j) x1 = fmaf(c9[j], W1[j * 64 + lane], x1);
        x0 = leaky_f(x0 * sc0 + sh0);
        x1 = leaky_f(x1 * sc1 + sh1);
        lse[k][lane] = x1;        // channels 0..63 : lse_part (W1 path)
        lse[k][64 + lane] = x0;   // channels 64..127 : new_points (W0 path)
    }
    __syncthreads();
    // scores raw: sraw[k][d] = sum_c lse[k][c]*Ws[c][d]
    int d = threadIdx.x & 127;
    int kg = threadIdx.x >> 7;   // 0..1 -> 8 k's each
    float acc[8];
#pragma unroll
    for (int i = 0; i < 8; ++i) acc[i] = 0.f;
    for (int c = 0; c < OUTC; ++c) {
        float w = Ws[c * OUTC + d];
#pragma unroll
        for (int i = 0; i < 8; ++i) acc[i] = fmaf(lse[kg * 8 + i][c], w, acc[i]);
    }
#pragma unroll
    for (int i = 0; i < 8; ++i) sraw[kg * 8 + i][d] = leaky_f(acc[i]);
    __syncthreads();
    if (threadIdx.x < OUTC) {
        int dd = threadIdx.x;
        float vals[KK];
        float mx = -3.4e38f;
#pragma unroll
        for (int k = 0; k < KK; ++k) { vals[k] = sraw[k][dd]; mx = fmaxf(mx, vals[k]); }
        float sum = 0.f;
#pragma unroll
        for (int k = 0; k < KK; ++k) { vals[k] = __expf(vals[k] - mx); sum += vals[k]; }
        float invs = 1.0f / sum;
        float feat = 0.f;
#pragma unroll
        for (int k = 0; k < KK; ++k) feat = fmaf(vals[k] * invs, lse[k][dd], feat);
        features1[(long)bs * OUTC + dd] = feat;
    }
}

// ---------------- mlp2 GEMM + stats -------------------
__global__ __launch_bounds__(256)
void mlp2_kernel(const float* __restrict__ features1,  // [B*S,128]
                 const float* __restrict__ W2, const float* __restrict__ b2,
                 float* __restrict__ x2,               // [B*S,128]
                 float* __restrict__ sums2)            // [2][128]
{
    int p0 = blockIdx.x * 16;
    __shared__ float f[16][OUTC];
    for (int i = threadIdx.x; i < 16 * OUTC; i += 256)
        f[i >> 7][i & 127] = features1[(long)p0 * OUTC + i];
    __syncthreads();
    int d = threadIdx.x & 127;
    int g = threadIdx.x >> 7;
    float acc[8];
#pragma unroll
    for (int i = 0; i < 8; ++i) acc[i] = b2[d];
    for (int c = 0; c < OUTC; ++c) {
        float w = W2[c * OUTC + d];
#pragma unroll
        for (int i = 0; i < 8; ++i) acc[i] = fmaf(f[g * 8 + i][c], w, acc[i]);
    }
    float s = 0.f, q = 0.f;
#pragma unroll
    for (int i = 0; i < 8; ++i) {
        x2[(long)(p0 + g * 8 + i) * OUTC + d] = acc[i];
        s += acc[i]; q += acc[i] * acc[i];
    }
    __shared__ float rs[2][2][OUTC];
    rs[0][g][d] = s; rs[1][g][d] = q;
    __syncthreads();
    if (threadIdx.x < OUTC) {
        atomicAdd(&sums2[d],        rs[0][0][d] + rs[0][1][d]);
        atomicAdd(&sums2[OUTC + d], rs[1][0][d] + rs[1][1][d]);
    }
}

__global__ void bn2_finalize(const float* __restrict__ sums2,
                             const float* __restrict__ g2, const float* __restrict__ be2,
                             float* __restrict__ ss2)
{
    int c = threadIdx.x;  // 128
    float inv = 1.0f / (float)(BB * SS);
    float m = sums2[c] * inv, v = sums2[OUTC + c] * inv - m * m;
    float sc = g2[c] / sqrtf(v + EPSF);
    ss2[c] = sc; ss2[OUTC + c] = be2[c] - m * sc;
}

__global__ __launch_bounds__(256)
void out1_kernel(const float* __restrict__ x2, const float* __restrict__ ss2,
                 float* __restrict__ out1)   // [B,128,S]
{
    int bc = blockIdx.x;
    int b = bc >> 7, c = bc & 127;
    float sc = ss2[c], sh = ss2[OUTC + c];
    for (int s = threadIdx.x; s < SS; s += 256) {
        float v = x2[((long)(b * SS + s)) * OUTC + c] * sc + sh;
        out1[(long)b * OUTC * SS + (long)c * SS + s] = leaky_f(v);
    }
}

extern "C" void kernel_launch(void* const* d_in, const int* in_sizes, int n_in,
                              void* d_out, int out_size, void* d_ws, size_t ws_size,
                              hipStream_t stream)
{
    const float* xyz    = (const float*)d_in[0];
    const float* points = (const float*)d_in[1];
    const float* W0  = (const float*)d_in[2];
    const float* b0  = (const float*)d_in[3];
    const float* g0  = (const float*)d_in[4];
    const float* be0 = (const float*)d_in[5];
    const float* W1  = (const float*)d_in[6];
    const float* b1  = (const float*)d_in[7];
    const float* g1  = (const float*)d_in[8];
    const float* be1 = (const float*)d_in[9];
    const float* Ws  = (const float*)d_in[10];
    const float* W2  = (const float*)d_in[11];
    const float* b2  = (const float*)d_in[12];
    const float* g2  = (const float*)d_in[13];
    const float* be2 = (const float*)d_in[14];

    char* ws = (char*)d_ws;
    int*   fps_i  = (int*)(ws + 0);              // 32768 B
    float* nxyz   = (float*)(ws + 32768);        // 98304 B
    int*   knn_i  = (int*)(ws + 131072);         // 524288 B
    float* sums01 = (float*)(ws + 655360);       // 1024 B
    float* sums2  = (float*)(ws + 656384);       // 1024 B
    float* ss01   = (float*)(ws + 657408);       // 1024 B
    float* ss2    = (float*)(ws + 658432);       // 1024 B
    float* feat1  = (float*)(ws + 659456);       // 4 MB
    float* x2     = (float*)(ws + 659456 + 4194304); // 4 MB

    float* out0 = (float*)d_out;                       // [B,3,S]
    float* out1 = out0 + (long)BB * 3 * SS;            // [B,128,S]
    float* out2 = out1 + (long)BB * OUTC * SS;         // [B,S] float idx

    hipMemsetAsync(sums01, 0, 2048, stream);  // zero sums01 + sums2 (contiguous)

    fps_kernel<<<BB, 1024, 0, stream>>>(xyz, fps_i, nxyz, out0, out2);
    knn_kernel<<<(BB * SS) / 4, 256, 0, stream>>>(xyz, nxyz, knn_i);
    mlp01_stats_kernel<<<2048, 256, 0, stream>>>(points, xyz, nxyz, knn_i, W0, b0, W1, b1, sums01);
    bn01_finalize<<<1, 64, 0, stream>>>(sums01, g0, be0, g1, be1, ss01);
    center_kernel<<<BB * SS, 256, 0, stream>>>(points, xyz, nxyz, knn_i, W0, b0, W1, b1, ss01, Ws, feat1);
    mlp2_kernel<<<(BB * SS) / 16, 256, 0, stream>>>(feat1, W2, b2, x2, sums2);
    bn2_finalize<<<1, 128, 0, stream>>>(sums2, g2, be2, ss2);
    out1_kernel<<<BB * OUTC, 256, 0, stream>>>(x2, ss2, out1);
}